// Round 2
// baseline (141.531 us; speedup 1.0000x reference)
//
#include <hip/hip_runtime.h>

// Problem constants (from reference)
#define BB 1024
#define SS 200
#define PQ_M 8
#define VALS 256
#define SUB_DIM 16
#define N_TOKENS (BB * SS)             // 204800
#define OUT_PER_TOKEN (PQ_M * SUB_DIM) // 128 floats = 512 B

typedef float f32x4 __attribute__((ext_vector_type(4)));
typedef int   i32x4 __attribute__((ext_vector_type(4)));

#define TOK_PER_BLOCK 128   // 1600 blocks over 256 CUs -> 6.25 blocks/CU
#define BLOCK_THREADS 256

// Single fused kernel, block-scoped producer/consumer:
//
// Phase 1 (gather): 2 threads per token. Thread (tok, half) loads the token's
//   id (2 adjacent lanes share -> one 4B load per pair), then one random 16B
//   gather from the 32MB code table (the only latency-bound access in the
//   kernel), packs 4 byte-codes into a u32, writes to LDS. 128 independent
//   chains per block, all in flight at once.
//
// Phase 2 (stream): 32 threads per token, 16 iterations over the block's 128
//   tokens. Per iteration: 4B LDS broadcast read (2 distinct addrs per 32-lane
//   group -> conflict-free), one float4 read from the hot 128KB centroid table
//   (each 4-lane quad shares a 64B line), one nontemporal float4 store --
//   each wave's 2 tokens form a contiguous 1KB segment.
//
// ~6 blocks/CU resident means one block's phase-1 HBM/L3 latency overlaps
// other blocks' phase-2 store streaming; no global sync, no extra dispatch,
// no workspace round-trip.
__global__ __launch_bounds__(BLOCK_THREADS) void pq_fused_kernel(
    const int*   __restrict__ ids,      // [N_TOKENS] item ids (int32)
    const i32x4* __restrict__ codes4,   // item_codes viewed as int4 (16B) pairs
    const f32x4* __restrict__ cent4,    // centroids as float4: [8*256*4]
    float*       __restrict__ out)      // [N_TOKENS * 128] fp32
{
    __shared__ unsigned int sc[TOK_PER_BLOCK * 2];  // 1KB: 8 packed codes/token

    const int base = blockIdx.x * TOK_PER_BLOCK;
    const int tid  = threadIdx.x;

    // ---- Phase 1: random code gather into LDS ----
    {
        const int tok  = tid >> 1;          // 0..127
        const int half = tid & 1;           // which 16B of the 32B code row
        const int id   = ids[base + tok];
        const i32x4 c  = codes4[(size_t)id * 2 + half];
        sc[tok * 2 + half] = (unsigned int)(c.x & 255)
                           | ((unsigned int)(c.y & 255) << 8)
                           | ((unsigned int)(c.z & 255) << 16)
                           | ((unsigned int)(c.w & 255) << 24);
    }
    __syncthreads();

    // ---- Phase 2: expand + stream out ----
    const int t   = tid & 31;      // float4 slot within token (0..31)
    const int grp = tid >> 5;      // token subgroup (0..7)
    const int m   = t >> 2;        // PQ dim 0..7
    const int c4  = t & 3;         // float4 chunk within sub-vector
    const int w   = m >> 2;        // which packed u32 holds this dim's code
    const int sh  = 8 * (m & 3);   // byte position within it

#pragma unroll
    for (int i = 0; i < TOK_PER_BLOCK / 8; ++i) {   // 16 iterations
        const int tok  = i * 8 + grp;
        const int code = (int)((sc[tok * 2 + w] >> sh) & 255u);
        const f32x4 v  = cent4[(m * VALS + code) * (SUB_DIM / 4) + c4];
        f32x4* dst = (f32x4*)(out + (size_t)(base + tok) * OUT_PER_TOKEN);
        __builtin_nontemporal_store(v, dst + t);
    }
}

extern "C" void kernel_launch(void* const* d_in, const int* in_sizes, int n_in,
                              void* d_out, int out_size, void* d_ws, size_t ws_size,
                              hipStream_t stream)
{
    const int*   ids   = (const int*)d_in[0];    // input_ids [1024,200]
    const int*   codes = (const int*)d_in[1];    // item_codes [1000002,8]
    const float* cent  = (const float*)d_in[2];  // centroids [8,256,16] fp32
    float*       out   = (float*)d_out;          // [1024,200,128] fp32

    const int grid = N_TOKENS / TOK_PER_BLOCK;   // 1600 blocks
    pq_fused_kernel<<<grid, BLOCK_THREADS, 0, stream>>>(
        ids, (const i32x4*)codes, (const f32x4*)cent, out);
}